// Round 12
// baseline (42.093 us; speedup 1.0000x reference)
//
#include <hip/hip_runtime.h>

#define NBINS  128               // uniform bins in x-space over [-6, 6]
#define NCLS   20
#define CDIM   21
#define HW     (512 * 512)
#define NPIX   (8 * HW)
#define NCHUNK 512
#define CHUNK  (NPIX / NCHUNK)   // 4096 pixels/block = 4 tiles of 1024; divides HW
#define HSZ    (NCLS * NBINS)    // 2560 packed u32 per block
#define XSCALE 10.6666667f       // 128/12
#define XBIAS  64.0f             // 6 * XSCALE

__device__ __forceinline__ float4 gld_f4(const float* p) {
    float4 r;
    asm volatile("global_load_dwordx4 %0, %1, off" : "=v"(r) : "v"(p));
    return r;
}
__device__ __forceinline__ int4 gld_i4(const int* p) {
    int4 r;
    asm volatile("global_load_dwordx4 %0, %1, off" : "=v"(r) : "v"(p));
    return r;
}

// One block = 4096 pixels (4 tiles of 1024), all 20 classes, binned in x-space
// (monotone in sigmoid; positives bin at -x on the symmetric grid).
// 16-phase counted-vmcnt pipeline, 3 groups ahead (vmcnt(15) steady state).
// Output: per-block packed u32 histogram (cnt lo16 | pos hi16) — plain stores,
// no atomics, no pre-zeroing needed (every slot overwritten every call).
__global__ __launch_bounds__(256, 2) void lovasz_hist(const float* __restrict__ pred,
                                                      const int* __restrict__ label,
                                                      unsigned* __restrict__ g_part) {
    __shared__ unsigned s_hist[HSZ];   // 10 KB
    const int tid = threadIdx.x;

    const long base = (long)blockIdx.x * CHUNK;
    const int  b    = (int)(base / HW);
    const long hw0  = base - (long)b * HW;
    const float* pbase = pred + ((long)b * CDIM + 1) * HW + hw0 + tid * 4;
    const int*   q     = label + base + tid * 4;

    // Prologue: 4 labels + G0 + G1 + G2 issued (19 outstanding).
    int4 l[4];
#pragma unroll
    for (int t = 0; t < 4; ++t) l[t] = gld_i4(q + t * 1024);
    float4 buf[4][5];
#pragma unroll
    for (int gg = 0; gg < 3; ++gg)
#pragma unroll
        for (int k = 0; k < 5; ++k)
            buf[gg][k] = gld_f4(pbase + (long)(gg * 5 + k) * HW);

    // zero LDS + barrier under the load latency
    for (int i = tid; i < HSZ; i += 256) s_hist[i] = 0u;
    __syncthreads();

    auto compute5 = [&](const float4* x, int cbase, const int4& lab) {
#pragma unroll
        for (int j = 0; j < 4; ++j) {
            const int lv = (j == 0) ? lab.x : (j == 1) ? lab.y : (j == 2) ? lab.z : lab.w;
#pragma unroll
            for (int k = 0; k < 5; ++k) {
                const float xv = (j == 0) ? x[k].x : (j == 1) ? x[k].y
                               : (j == 2) ? x[k].z : x[k].w;
                const bool  pos = (lv == cbase + k + 1);
                const float t   = pos ? -xv : xv;     // error = sigmoid(t)
                const float bf  = fminf(fmaxf(__builtin_fmaf(t, XSCALE, XBIAS), 0.0f), 127.0f);
                const int   bin = (int)bf;
                atomicAdd(&s_hist[(cbase + k) * NBINS + bin], pos ? 0x10001u : 1u);
            }
        }
    };

#pragma unroll
    for (int g = 0; g < 16; ++g) {
        if (g + 3 < 16) {       // issue group g+3 into buf[(g+3)%4]
            const int gg = g + 3;
#pragma unroll
            for (int k = 0; k < 5; ++k)
                buf[gg % 4][k] =
                    gld_f4(pbase + (long)((gg & 3) * 5 + k) * HW + (gg >> 2) * 1024);
        }
        if (g < 13)       asm volatile("s_waitcnt vmcnt(15)" ::: "memory");
        else if (g == 13) asm volatile("s_waitcnt vmcnt(10)" ::: "memory");
        else if (g == 14) asm volatile("s_waitcnt vmcnt(5)" ::: "memory");
        else              asm volatile("s_waitcnt vmcnt(0)" ::: "memory");
        __builtin_amdgcn_sched_barrier(0);
        compute5(buf[g % 4], (g & 3) * 5, l[g >> 2]);
    }

    __syncthreads();

    // Plain coalesced stores of the packed per-block histogram.
    unsigned* gp = g_part + (size_t)blockIdx.x * HSZ;
#pragma unroll
    for (int i = tid; i < HSZ; i += 256) gp[i] = s_hist[i];
}

// Per-class (20 blocks, 1024 threads): sum 512 packed replicas per bin, then
// descending wave-shfl prefix scan + Lovasz-grad weighted sum.
__global__ __launch_bounds__(1024) void lovasz_scan(const unsigned* __restrict__ g_part,
                                                    float* __restrict__ cls_out) {
    const int c    = blockIdx.x;
    const int tid  = threadIdx.x;
    const int rch  = tid >> 7;       // replica chunk 0..7 (64 replicas each)
    const int bin  = tid & 127;
    const unsigned* gp = g_part + (size_t)c * NBINS + bin;

    // 64 replicas in 8 batches of 8 packed adds (8*4096 < 2^16: no overflow).
    unsigned vc = 0, vp = 0;
    const int r0 = rch * 64;
#pragma unroll
    for (int bt = 0; bt < 8; ++bt) {
        unsigned pk = 0;
#pragma unroll
        for (int k = 0; k < 8; ++k)
            pk += gp[(size_t)(r0 + bt * 8 + k) * HSZ];
        vc += pk & 0xFFFFu;
        vp += pk >> 16;
    }
    __shared__ unsigned s_c[8][128], s_p[8][128];
    s_c[rch][bin] = vc;
    s_p[rch][bin] = vp;
    __syncthreads();

    // First 128 threads: d = tid is the DESCENDING position, bin = 127 - d.
    const int d    = tid;
    const int bn   = 127 - d;
    const int lane = tid & 63;
    const int w    = tid >> 6;       // wave 0 or 1
    int tc = 0, tp = 0;
    if (tid < 128) {
#pragma unroll
        for (int r = 0; r < 8; ++r) { tc += s_c[r][bn]; tp += s_p[r][bn]; }
    }
    int ic = tc, ip = tp;            // inclusive scan within wave
#pragma unroll
    for (int dd = 1; dd < 64; dd <<= 1) {
        const int t0 = __shfl_up(ic, dd, 64);
        const int t1 = __shfl_up(ip, dd, 64);
        if (lane >= dd) { ic += t0; ip += t1; }
    }
    __shared__ int wc[2], wp[2];
    __shared__ float wsum[2];
    if (tid < 128 && lane == 63) { wc[w] = ic; wp[w] = ip; }
    __syncthreads();

    float contrib = 0.0f;
    int G = 0;
    if (tid < 128) {
        G = wp[0] + wp[1];
        if (w == 1) { ic += wc[0]; ip += wp[0]; }
        const int ec = ic - tc, ep = ip - tp;        // exclusive prefix at d
        if (G > 0 && tc > 0) {
            const float fG = (float)G;
            auto J = [&](int i, int m) {
                return 1.0f - (fG - (float)m) / (fG + (float)(i - m));
            };
            const float xm = ((float)bn + 0.5f) * (12.0f / (float)NBINS) - 6.0f;
            const float em = 1.0f / (1.0f + __expf(-xm));
            contrib = em * (J(ec + tc, ep + tp) - J(ec, ep));
        }
    }
#pragma unroll
    for (int dd = 32; dd > 0; dd >>= 1) contrib += __shfl_down(contrib, dd, 64);
    if (tid < 128 && lane == 0) wsum[w] = contrib;
    __syncthreads();
    if (tid == 0) {
        cls_out[c * 2]     = wsum[0] + wsum[1];
        cls_out[c * 2 + 1] = (G > 0) ? 1.0f : 0.0f;
    }
}

__global__ void lovasz_final(const float* __restrict__ cls_out, float* __restrict__ out) {
    const int lane = threadIdx.x & 63;
    float s = 0.0f, n = 0.0f;
    if (lane < NCLS) { s = cls_out[lane * 2]; n = cls_out[lane * 2 + 1]; }
#pragma unroll
    for (int dd = 32; dd > 0; dd >>= 1) {
        s += __shfl_down(s, dd, 64);
        n += __shfl_down(n, dd, 64);
    }
    if (threadIdx.x == 0) out[0] = s / n;
}

extern "C" void kernel_launch(void* const* d_in, const int* in_sizes, int n_in,
                              void* d_out, int out_size, void* d_ws, size_t ws_size,
                              hipStream_t stream) {
    const float* pred  = (const float*)d_in[0];
    const int*   label = (const int*)d_in[1];

    unsigned* g_part = (unsigned*)d_ws;                       // 512*2560*4B = 5.25 MB
    float*    cls_out = (float*)(g_part + (size_t)NCHUNK * HSZ);
    float*    out     = (float*)d_out;

    lovasz_hist<<<NCHUNK, 256, 0, stream>>>(pred, label, g_part);
    lovasz_scan<<<NCLS, 1024, 0, stream>>>(g_part, cls_out);
    lovasz_final<<<1, 64, 0, stream>>>(cls_out, out);
}

// Round 13
// 39.818 us; speedup vs baseline: 1.0571x; 1.0571x over previous
//
#include <hip/hip_runtime.h>

#define NBINS  128               // uniform bins in x-space over [-6, 6]
#define NCLS   20
#define CDIM   21
#define HW     (512 * 512)
#define NPIX   (8 * HW)
#define NCHUNK 512
#define CHUNK  (NPIX / NCHUNK)   // 4096 pixels/block; divides HW
#define HSZ    (NCLS * NBINS)    // 2560 packed u32 per block
#define XSCALE 10.6666667f       // 128/12
#define XBIAS  64.0f             // 6 * XSCALE

__device__ __forceinline__ float4 gld_f4(const float* p) {
    float4 r;
    asm volatile("global_load_dwordx4 %0, %1, off" : "=v"(r) : "v"(p));
    return r;
}
__device__ __forceinline__ int4 gld_i4(const int* p) {
    int4 r;
    asm volatile("global_load_dwordx4 %0, %1, off" : "=v"(r) : "v"(p));
    return r;
}

// One block = 4096 pixels via 512 threads (2 tiles of 2048 px), all 20 classes,
// binned in x-space (monotone in sigmoid; positives bin at -x, symmetric grid).
// 8-phase counted-vmcnt pipeline (tile g/4, channels (g%4)*5..+4), 2 groups
// ahead -> vmcnt(10) steady. 16 waves/CU (2 blocks x 8 waves). Output: packed
// per-block u32 histogram (cnt lo16 | pos hi16), plain stores, no pre-zeroing.
__global__ __launch_bounds__(512, 4) void lovasz_hist(const float* __restrict__ pred,
                                                      const int* __restrict__ label,
                                                      unsigned* __restrict__ g_part) {
    __shared__ unsigned s_hist[HSZ];   // 10 KB
    const int tid = threadIdx.x;

    const long base = (long)blockIdx.x * CHUNK;
    const int  b    = (int)(base / HW);
    const long hw0  = base - (long)b * HW;
    const float* pbase = pred + ((long)b * CDIM + 1) * HW + hw0 + tid * 4;
    const int*   q     = label + base + tid * 4;

    // Prologue: 2 labels + G0 + G1 issued (12 outstanding).
    int4 l[2];
    l[0] = gld_i4(q);
    l[1] = gld_i4(q + 2048);
    float4 buf[3][5];
#pragma unroll
    for (int gg = 0; gg < 2; ++gg)
#pragma unroll
        for (int k = 0; k < 5; ++k)
            buf[gg][k] = gld_f4(pbase + (long)(gg * 5 + k) * HW);

    // zero LDS + barrier under the load latency
    for (int i = tid; i < HSZ; i += 512) s_hist[i] = 0u;
    __syncthreads();

    auto compute5 = [&](const float4* x, int cbase, const int4& lab) {
#pragma unroll
        for (int j = 0; j < 4; ++j) {
            const int lv = (j == 0) ? lab.x : (j == 1) ? lab.y : (j == 2) ? lab.z : lab.w;
#pragma unroll
            for (int k = 0; k < 5; ++k) {
                const float xv = (j == 0) ? x[k].x : (j == 1) ? x[k].y
                               : (j == 2) ? x[k].z : x[k].w;
                const bool  pos = (lv == cbase + k + 1);
                const float t   = pos ? -xv : xv;     // error = sigmoid(t)
                const float bf  = fminf(fmaxf(__builtin_fmaf(t, XSCALE, XBIAS), 0.0f), 127.0f);
                const int   bin = (int)bf;
                atomicAdd(&s_hist[(cbase + k) * NBINS + bin], pos ? 0x10001u : 1u);
            }
        }
    };

#pragma unroll
    for (int g = 0; g < 8; ++g) {
        if (g + 2 < 8) {        // issue group g+2 into buf[(g+2)%3]
            const int gg = g + 2;
#pragma unroll
            for (int k = 0; k < 5; ++k)
                buf[gg % 3][k] =
                    gld_f4(pbase + (long)((gg & 3) * 5 + k) * HW + (gg >> 2) * 2048);
        }
        if (g < 6)       asm volatile("s_waitcnt vmcnt(10)" ::: "memory");
        else if (g == 6) asm volatile("s_waitcnt vmcnt(5)" ::: "memory");
        else             asm volatile("s_waitcnt vmcnt(0)" ::: "memory");
        __builtin_amdgcn_sched_barrier(0);
        compute5(buf[g % 3], (g & 3) * 5, l[g >> 2]);
    }

    __syncthreads();

    // Plain coalesced stores of the packed per-block histogram.
    unsigned* gp = g_part + (size_t)blockIdx.x * HSZ;
    for (int i = tid; i < HSZ; i += 512) gp[i] = s_hist[i];
}

// Parallel reduce: P[512][2560] packed -> H[2560] u64 (cnt lo32 | pos hi32).
// 160 blocks x 256 thr; block bb owns 16 bins; thread t: bin bb*16+(t&15),
// replica chunk t>>4 (32 replicas, unpacked every 8 to avoid 16-bit overflow).
__global__ __launch_bounds__(256) void lovasz_reduce(const unsigned* __restrict__ g_part,
                                                     unsigned long long* __restrict__ H) {
    const int t  = threadIdx.x;
    const int i  = blockIdx.x * 16 + (t & 15);
    const int rc = t >> 4;            // 0..15
    const unsigned* gp = g_part + i;

    unsigned vc = 0, vp = 0;
#pragma unroll
    for (int bt = 0; bt < 4; ++bt) {
        unsigned pk = 0;
#pragma unroll
        for (int k = 0; k < 8; ++k)
            pk += gp[(size_t)(rc * 32 + bt * 8 + k) * HSZ];
        vc += pk & 0xFFFFu;
        vp += pk >> 16;
    }
    __shared__ unsigned s_c[16][16], s_p[16][16];
    s_c[rc][t & 15] = vc;
    s_p[rc][t & 15] = vp;
    __syncthreads();
    if (t < 16) {
        unsigned c = 0, p = 0;
#pragma unroll
        for (int r = 0; r < 16; ++r) { c += s_c[r][t]; p += s_p[r][t]; }
        H[blockIdx.x * 16 + t] = (unsigned long long)c | ((unsigned long long)p << 32);
    }
}

// Fused scan+final: one wave per class (2 bins/lane), shfl butterfly prefix
// scan in descending-error order, Lovasz-grad weighted sum, block reduce.
__global__ __launch_bounds__(1024) void lovasz_scan(const unsigned long long* __restrict__ H,
                                                    float* __restrict__ out) {
    __shared__ float cls_sum[NCLS];
    __shared__ float cls_cnt[NCLS];
    const int wid  = threadIdx.x >> 6;
    const int lane = threadIdx.x & 63;

#pragma unroll
    for (int it = 0; it < 2; ++it) {
        const int cls = it * 16 + wid;
        if (cls < NCLS) {
            // lane covers descending positions d0=2*lane (bin 127-2l), d1 (bin 126-2l)
            const int bin_lo = 126 - 2 * lane;
            const ulonglong2 v = *reinterpret_cast<const ulonglong2*>(H + cls * NBINS + bin_lo);
            const int vc1 = (int)(v.x & 0xFFFFFFFFull), vp1 = (int)(v.x >> 32);  // d1
            const int vc0 = (int)(v.y & 0xFFFFFFFFull), vp0 = (int)(v.y >> 32);  // d0
            const int sc = vc0 + vc1, sp = vp0 + vp1;
            int ic = sc, ip = sp;                 // inclusive wave scan over lanes
#pragma unroll
            for (int d = 1; d < 64; d <<= 1) {
                const int tc = __shfl_up(ic, d, 64);
                const int tp = __shfl_up(ip, d, 64);
                if (lane >= d) { ic += tc; ip += tp; }
            }
            const int G   = __shfl(ip, 63, 64);         // total positives
            const int ec0 = ic - sc, ep0 = ip - sp;     // exclusive prefix at d0
            float contrib = 0.0f;
            if (G > 0) {
                const float fG = (float)G;
                auto J = [&](int i, int m) {
                    return 1.0f - (fG - (float)m) / (fG + (float)(i - m));
                };
                auto EMID = [&](int bn) {
                    const float xm = ((float)bn + 0.5f) * (12.0f / (float)NBINS) - 6.0f;
                    return 1.0f / (1.0f + __expf(-xm));
                };
                if (vc0) {
                    contrib += EMID(127 - 2 * lane) *
                               (J(ec0 + vc0, ep0 + vp0) - J(ec0, ep0));
                }
                if (vc1) {
                    const int ec = ec0 + vc0, ep = ep0 + vp0;
                    contrib += EMID(126 - 2 * lane) *
                               (J(ec + vc1, ep + vp1) - J(ec, ep));
                }
            }
#pragma unroll
            for (int d = 32; d > 0; d >>= 1) contrib += __shfl_down(contrib, d, 64);
            if (lane == 0) {
                cls_sum[cls] = contrib;
                cls_cnt[cls] = (G > 0) ? 1.0f : 0.0f;
            }
        }
    }
    __syncthreads();
    if (threadIdx.x == 0) {
        float s = 0.0f, n = 0.0f;
        for (int c = 0; c < NCLS; ++c) { s += cls_sum[c]; n += cls_cnt[c]; }
        out[0] = s / n;
    }
}

extern "C" void kernel_launch(void* const* d_in, const int* in_sizes, int n_in,
                              void* d_out, int out_size, void* d_ws, size_t ws_size,
                              hipStream_t stream) {
    const float* pred  = (const float*)d_in[0];
    const int*   label = (const int*)d_in[1];

    unsigned* g_part = (unsigned*)d_ws;                       // 512*2560*4B = 5.25 MB
    unsigned long long* H = (unsigned long long*)(g_part + (size_t)NCHUNK * HSZ);
    float* out = (float*)d_out;

    lovasz_hist<<<NCHUNK, 512, 0, stream>>>(pred, label, g_part);
    lovasz_reduce<<<HSZ / 16, 256, 0, stream>>>(g_part, H);
    lovasz_scan<<<1, 1024, 0, stream>>>(H, out);
}